// Round 1
// baseline (578.601 us; speedup 1.0000x reference)
//
#include <hip/hip_runtime.h>
#include <hip/hip_bf16.h>
#include <stdint.h>

#define BATCH   2048
#define NIN     2048
#define NGATES  8192
#define NCOL    16384   // NGATES*2

typedef short s16x8 __attribute__((ext_vector_type(8)));   // 8 bf16 (4 VGPRs)
typedef float f32x4 __attribute__((ext_vector_type(4)));

__device__ __forceinline__ void gload_lds16(const void* g, void* l) {
  __builtin_amdgcn_global_load_lds(
      (const __attribute__((address_space(1))) void*)g,
      (__attribute__((address_space(3))) void*)l,
      16, 0, 0);
}

__device__ __forceinline__ unsigned short f2bf(float f) {
  __hip_bfloat16 h = __float2bfloat16(f);
  return __builtin_bit_cast(unsigned short, h);
}

// ---------------------------------------------------------------------------
// Kernel 1: per-gate bilinear coefficients from softmax(w[:,g]).
// out = P0 + P1*A + P2*B + P3*A*B  (gates are all bilinear in A,B)
// ---------------------------------------------------------------------------
__global__ __launch_bounds__(256) void gate_coeff_k(const float* __restrict__ w,
                                                    float4* __restrict__ coeff) {
  const int g = blockIdx.x * 256 + threadIdx.x;
  float e[16];
  float s = 0.f;
#pragma unroll
  for (int k = 0; k < 16; ++k) { e[k] = __expf(w[k * NGATES + g]); s += e[k]; }
  const float inv = 1.0f / s;
#pragma unroll
  for (int k = 0; k < 16; ++k) e[k] *= inv;
  const float P0 = e[8] + e[9] + e[10] + e[11] + e[12] + e[13] + e[14] + e[15];
  const float P1 = e[2] + e[3] + e[6] + e[7] - e[8] - e[9] - e[12] - e[13];
  const float P2 = e[4] + e[5] + e[6] + e[7] - e[8] - e[9] - e[10] - e[11];
  const float P3 = e[1] - e[2] - e[4] - 2.f * e[6] - e[7] + e[8] + 2.f * e[9]
                 + e[11] + e[13] - e[14];
  coeff[g] = make_float4(P0, P1, P2, P3);
}

// ---------------------------------------------------------------------------
// Kernel 2: x (fp32) -> bf16, row-major [B][K] (A-operand layout)
// ---------------------------------------------------------------------------
__global__ __launch_bounds__(256) void cvt_x_k(const float4* __restrict__ x,
                                               ushort4* __restrict__ xb) {
  const int i = blockIdx.x * 256 + threadIdx.x;
  float4 v = x[i];
  ushort4 h;
  h.x = f2bf(v.x); h.y = f2bf(v.y); h.z = f2bf(v.z); h.w = f2bf(v.w);
  xb[i] = h;
}

// ---------------------------------------------------------------------------
// Kernel 3: e = exp(c) (no max-sub needed: c ~ N(0,1), exp range tiny for fp32),
// store bf16 TRANSPOSED as expcT[n][k] (k-contiguous -> ds_read_b128 B-frags),
// accumulate per-column partial sums of the *bf16-rounded* values (so columns
// are exact convex combinations after scaling -> kills correlated bf16 error).
// Grid: (NCOL/64, 4 row-quarters). LDS tile 64x64, pad 68 to dodge conflicts.
// ---------------------------------------------------------------------------
__global__ __launch_bounds__(256) void softmax_t_k(const float* __restrict__ c,
                                                   unsigned short* __restrict__ bT,
                                                   float* __restrict__ psums) {
  __shared__ unsigned short T[64 * 68];
  __shared__ float psum[4][64];
  const int t = threadIdx.x;
  const int cloc = t & 63;    // column within strip
  const int rgrp = t >> 6;    // 0..3
  const int n0 = blockIdx.x * 64;
  const int q  = blockIdx.y;  // row quarter (512 rows)
  float s = 0.f;
  for (int it = 0; it < 8; ++it) {
    const int i0 = q * 512 + it * 64;
#pragma unroll
    for (int j = 0; j < 16; ++j) {
      const int r = rgrp + 4 * j;                       // 0..63
      float v = c[(size_t)(i0 + r) * NCOL + n0 + cloc]; // coalesced row read
      unsigned short h = f2bf(__expf(v));
      s += __bfloat162float(__builtin_bit_cast(__hip_bfloat16, h));
      T[cloc * 68 + r] = h;                             // transposed, 2-way max
    }
    __syncthreads();
    const int ko = (t & 7) * 8;                         // bf16 offset in k
#pragma unroll
    for (int pass = 0; pass < 2; ++pass) {
      const int n = pass * 32 + (t >> 3);               // 0..63
      const uint64_t* sp =
          (const uint64_t*)((const char*)T + n * 136 + ko * 2);
      uint64_t q0 = sp[0], q1 = sp[1];
      uint64_t* dp = (uint64_t*)(bT + (size_t)(n0 + n) * NIN + i0 + ko);
      dp[0] = q0; dp[1] = q1;                           // coalesced 128B/row
    }
    __syncthreads();
  }
  psum[rgrp][cloc] = s;
  __syncthreads();
  if (t < 64) {
    float tot = psum[0][t] + psum[1][t] + psum[2][t] + psum[3][t];
    psums[(size_t)q * NCOL + n0 + t] = tot;
  }
}

// ---------------------------------------------------------------------------
// Kernel 4: fold row-quarter partials -> invsum[n] = 1/sum
// ---------------------------------------------------------------------------
__global__ __launch_bounds__(256) void inv_k(const float* __restrict__ psums,
                                             float* __restrict__ invs) {
  const int n = blockIdx.x * 256 + threadIdx.x;
  invs[n] = 1.0f / (psums[n] + psums[NCOL + n] + psums[2 * NCOL + n] +
                    psums[3 * NCOL + n]);
}

// ---------------------------------------------------------------------------
// Kernel 5: bf16 MFMA GEMM (m97 structure: 128x128 tile, BK=32,
// global_load_lds width=16) + fused gate epilogue.
// C cols interleave A(even)/B(odd); pair via __shfl_xor(.,1); write out
// coalesced through padded LDS staging.
// ---------------------------------------------------------------------------
__global__ __launch_bounds__(256) void gemm_gate_k(
    const unsigned short* __restrict__ xb,   // [2048][2048] bf16
    const unsigned short* __restrict__ bT,   // [16384][2048] bf16
    const float* __restrict__ invs,          // [16384]
    const float4* __restrict__ coeff,        // [8192]
    float* __restrict__ out) {               // [2048][8192]
  __shared__ __align__(16) char smem[17408]; // As(8K)+Bs(8K) | outS 64x68 f32
  float* outS = (float*)smem;

  const int t = threadIdx.x;
  const int l = t & 63;
  const int w = t >> 6;
  const int wm = w >> 1, wn = w & 1;
  const int m0 = blockIdx.y * 128;
  const int n0 = blockIdx.x * 128;

  f32x4 acc[4][4] = {};

  // staging map: thread t covers A/B tile row (t>>2), 16B chunk (t&3)
  const int srow = t >> 2;
  const int scol = (t & 3) * 8;
  const unsigned short* gA = xb + (size_t)(m0 + srow) * NIN + scol;
  const unsigned short* gB = bT + (size_t)(n0 + srow) * NIN + scol;
  char* lA0 = smem + t * 16;          // As rows 0..63   (base + lane*16)
  char* lA1 = smem + 4096 + t * 16;   // As rows 64..127
  char* lB0 = smem + 8192 + t * 16;
  char* lB1 = smem + 12288 + t * 16;

  const int fr = l & 15;
  const int koff = (l >> 4) * 8;

  for (int kt = 0; kt < NIN / 32; ++kt) {
    const int kb = kt * 32;
    gload_lds16(gA + kb, lA0);
    gload_lds16(gA + kb + 64 * NIN, lA1);
    gload_lds16(gB + kb, lB0);
    gload_lds16(gB + kb + 64 * NIN, lB1);
    __syncthreads();
    s16x8 af[4], bf[4];
#pragma unroll
    for (int i = 0; i < 4; ++i) {
      af[i] = *(const s16x8*)(smem + ((64 * wm + 16 * i + fr) * 32 + koff) * 2);
      bf[i] = *(const s16x8*)(smem + 8192 +
                              ((64 * wn + 16 * i + fr) * 32 + koff) * 2);
    }
#pragma unroll
    for (int i = 0; i < 4; ++i)
#pragma unroll
      for (int j = 0; j < 4; ++j)
        acc[i][j] = __builtin_amdgcn_mfma_f32_16x16x32_bf16(af[i], bf[j],
                                                            acc[i][j], 0, 0, 0);
    __syncthreads();
  }

  // epilogue preloads (per n-tile j): invsum for my column, coeffs for my gate
  float  is4[4];
  float4 cf4[4];
  const int g0 = n0 >> 1;
#pragma unroll
  for (int j = 0; j < 4; ++j) {
    const int colg = n0 + 64 * wn + 16 * j + fr;
    is4[j] = invs[colg];
    cf4[j] = coeff[colg >> 1];
  }

  for (int half = 0; half < 2; ++half) {
    if (wm == half) {
#pragma unroll
      for (int i = 0; i < 4; ++i)
#pragma unroll
        for (int j = 0; j < 4; ++j)
#pragma unroll
          for (int r = 0; r < 4; ++r) {
            float v = acc[i][j][r] * is4[j];   // normalized y
            float o = __shfl_xor(v, 1);        // partner column
            if (!(l & 1)) {                    // even lane: col=2g -> A, o=B
              float A = v, B = o;
              float4 p = cf4[j];
              float res = p.x + p.y * A + p.z * B + p.w * A * B;
              const int row = 16 * i + ((l >> 4) << 2) + r;       // 0..63
              const int col = 32 * wn + 8 * j + (fr >> 1);        // 0..63
              outS[row * 68 + col] = res;
            }
          }
    }
    __syncthreads();
#pragma unroll
    for (int it = 0; it < 4; ++it) {
      const int row = it * 16 + (t >> 4);
      const int c4 = (t & 15) * 4;
      float4 vv = *(const float4*)&outS[row * 68 + c4];
      *(float4*)&out[(size_t)(m0 + half * 64 + row) * NGATES + g0 + c4] = vv;
    }
    __syncthreads();
  }
}

// ---------------------------------------------------------------------------
extern "C" void kernel_launch(void* const* d_in, const int* in_sizes, int n_in,
                              void* d_out, int out_size, void* d_ws,
                              size_t ws_size, hipStream_t stream) {
  const float* x = (const float*)d_in[0];   // [2048][2048]
  const float* w = (const float*)d_in[1];   // [16][8192]
  const float* c = (const float*)d_in[2];   // [2048][8192][2]
  float* out = (float*)d_out;               // [2048][8192]
  char* ws = (char*)d_ws;

  // workspace layout (all 16B-aligned offsets)
  unsigned short* xb   = (unsigned short*)(ws);               // 8,388,608 B
  unsigned short* bT   = (unsigned short*)(ws + 8388608);     // 67,108,864 B
  float*          invs = (float*)(ws + 75497472);             // 65,536 B
  float4*         cf   = (float4*)(ws + 75563008);            // 131,072 B
  float*          ps   = (float*)(ws + 75694080);             // 262,144 B
  // total: 75,956,224 B

  gate_coeff_k<<<NGATES / 256, 256, 0, stream>>>(w, cf);
  cvt_x_k<<<(BATCH * NIN / 4) / 256, 256, 0, stream>>>((const float4*)x,
                                                       (ushort4*)xb);
  dim3 sg(NCOL / 64, 4);
  softmax_t_k<<<sg, 256, 0, stream>>>(c, bT, ps);
  inv_k<<<NCOL / 256, 256, 0, stream>>>(ps, invs);
  dim3 gg(NCOL / 128, BATCH / 128);
  gemm_gate_k<<<gg, 256, 0, stream>>>(xb, bT, invs, cf, out);
}

// Round 2
// 456.938 us; speedup vs baseline: 1.2663x; 1.2663x over previous
//
#include <hip/hip_runtime.h>
#include <hip/hip_bf16.h>
#include <stdint.h>

#define BATCH   2048
#define NIN     2048
#define NGATES  8192
#define NCOL    16384   // NGATES*2

typedef short s16x8 __attribute__((ext_vector_type(8)));   // 8 bf16 (4 VGPRs)
typedef float f32x4 __attribute__((ext_vector_type(4)));

__device__ __forceinline__ void gload_lds16(const void* g, void* l) {
  __builtin_amdgcn_global_load_lds(
      (const __attribute__((address_space(1))) void*)g,
      (__attribute__((address_space(3))) void*)l,
      16, 0, 0);
}

__device__ __forceinline__ unsigned short f2bf(float f) {
  __hip_bfloat16 h = __float2bfloat16(f);
  return __builtin_bit_cast(unsigned short, h);
}
__device__ __forceinline__ float bf2f(unsigned short u) {
  return __bfloat162float(__builtin_bit_cast(__hip_bfloat16, u));
}

// ---------------------------------------------------------------------------
// Kernel 1: per-gate bilinear coefficients from softmax(w[:,g]).
// out = P0 + P1*A + P2*B + P3*A*B  (all 16 gates are bilinear in A,B)
// ---------------------------------------------------------------------------
__global__ __launch_bounds__(256) void gate_coeff_k(const float* __restrict__ w,
                                                    float4* __restrict__ coeff) {
  const int g = blockIdx.x * 256 + threadIdx.x;
  float e[16];
  float s = 0.f;
#pragma unroll
  for (int k = 0; k < 16; ++k) { e[k] = __expf(w[k * NGATES + g]); s += e[k]; }
  const float inv = 1.0f / s;
#pragma unroll
  for (int k = 0; k < 16; ++k) e[k] *= inv;
  const float P0 = e[8] + e[9] + e[10] + e[11] + e[12] + e[13] + e[14] + e[15];
  const float P1 = e[2] + e[3] + e[6] + e[7] - e[8] - e[9] - e[12] - e[13];
  const float P2 = e[4] + e[5] + e[6] + e[7] - e[8] - e[9] - e[10] - e[11];
  const float P3 = e[1] - e[2] - e[4] - 2.f * e[6] - e[7] + e[8] + 2.f * e[9]
                 + e[11] + e[13] - e[14];
  coeff[g] = make_float4(P0, P1, P2, P3);
}

// ---------------------------------------------------------------------------
// Kernel 2: x (fp32) -> bf16, row-major [B][K]
// ---------------------------------------------------------------------------
__global__ __launch_bounds__(256) void cvt_x_k(const float4* __restrict__ x,
                                               ushort4* __restrict__ xb) {
  const int i = blockIdx.x * 256 + threadIdx.x;
  float4 v = x[i];
  ushort4 h;
  h.x = f2bf(v.x); h.y = f2bf(v.y); h.z = f2bf(v.z); h.w = f2bf(v.w);
  xb[i] = h;
}

// ---------------------------------------------------------------------------
// Kernel 3: e = exp(c) bf16, TRANSPOSED to expcT[n][k]; per-column partial
// sums of the bf16-rounded values. float4 reads, packed u32 LDS writes.
// Grid: (NCOL/64, 4 row-quarters of 512).
// ---------------------------------------------------------------------------
__global__ __launch_bounds__(256) void softmax_t_k(const float* __restrict__ c,
                                                   unsigned short* __restrict__ bT,
                                                   float* __restrict__ psums) {
  __shared__ unsigned int T32[64 * 34];   // [n][kpair], row stride 136 B
  __shared__ float psumS[16][68];
  const int t = threadIdx.x;
  const int n4 = (t & 15) * 4;   // 4 consecutive columns per thread
  const int kr = t >> 4;         // 0..15
  const int n0 = blockIdx.x * 64;
  const int q  = blockIdx.y;     // row quarter (512 rows)
  float s0 = 0.f, s1 = 0.f, s2 = 0.f, s3 = 0.f;

  for (int it = 0; it < 8; ++it) {
    const int i0 = q * 512 + it * 64;
#pragma unroll
    for (int p = 0; p < 2; ++p) {
      const int r0 = p * 32 + kr * 2;
      const float4 a = *(const float4*)&c[(size_t)(i0 + r0) * NCOL + n0 + n4];
      const float4 b = *(const float4*)&c[(size_t)(i0 + r0 + 1) * NCOL + n0 + n4];
      const unsigned int ax = f2bf(__expf(a.x)), bx = f2bf(__expf(b.x));
      const unsigned int ay = f2bf(__expf(a.y)), by = f2bf(__expf(b.y));
      const unsigned int az = f2bf(__expf(a.z)), bz = f2bf(__expf(b.z));
      const unsigned int aw = f2bf(__expf(a.w)), bw = f2bf(__expf(b.w));
      s0 += bf2f(ax) + bf2f(bx);
      s1 += bf2f(ay) + bf2f(by);
      s2 += bf2f(az) + bf2f(bz);
      s3 += bf2f(aw) + bf2f(bw);
      const int kp = p * 16 + kr;
      T32[(n4 + 0) * 34 + kp] = ax | (bx << 16);
      T32[(n4 + 1) * 34 + kp] = ay | (by << 16);
      T32[(n4 + 2) * 34 + kp] = az | (bz << 16);
      T32[(n4 + 3) * 34 + kp] = aw | (bw << 16);
    }
    __syncthreads();
    const int ko = (t & 7) * 8;
#pragma unroll
    for (int pass = 0; pass < 2; ++pass) {
      const int n = pass * 32 + (t >> 3);
      const uint64_t* sp =
          (const uint64_t*)((const char*)T32 + n * 136 + ko * 2);
      uint64_t q0 = sp[0], q1 = sp[1];
      uint64_t* dp = (uint64_t*)(bT + (size_t)(n0 + n) * NIN + i0 + ko);
      dp[0] = q0; dp[1] = q1;
    }
    __syncthreads();
  }
  psumS[kr][n4 + 0] = s0;
  psumS[kr][n4 + 1] = s1;
  psumS[kr][n4 + 2] = s2;
  psumS[kr][n4 + 3] = s3;
  __syncthreads();
  if (t < 64) {
    float tot = 0.f;
#pragma unroll
    for (int k2 = 0; k2 < 16; ++k2) tot += psumS[k2][t];
    psums[(size_t)q * NCOL + n0 + t] = tot;
  }
}

// ---------------------------------------------------------------------------
// Kernel 4: fold row-quarter partials -> invsum[n] = 1/sum
// ---------------------------------------------------------------------------
__global__ __launch_bounds__(256) void inv_k(const float* __restrict__ psums,
                                             float* __restrict__ invs) {
  const int n = blockIdx.x * 256 + threadIdx.x;
  invs[n] = 1.0f / (psums[n] + psums[NCOL + n] + psums[2 * NCOL + n] +
                    psums[3 * NCOL + n]);
}

// ---------------------------------------------------------------------------
// Kernel 5: bf16 MFMA GEMM, 128x128 tile, BK=64, TRUE 2-stage pipeline:
// double-buffered LDS, global_load_lds for iter k+1 issued after a raw
// s_waitcnt vmcnt(0)+s_barrier (loads drain one full compute-phase after
// issue -> stall = max(0, L - C)). Row-parity XOR keeps LDS banks at the
// proven BK=32 pattern. XCD-compact grid swizzle for L2 slab sharing.
// ---------------------------------------------------------------------------
__global__ __launch_bounds__(256, 2) void gemm_gate_k(
    const unsigned short* __restrict__ xb,   // [2048][2048] bf16
    const unsigned short* __restrict__ bT,   // [16384][2048] bf16
    const float* __restrict__ invs,          // [16384]
    const float4* __restrict__ coeff,        // [8192]
    float* __restrict__ out) {               // [2048][8192]
  __shared__ __align__(16) char smem[65536]; // 2 x (As 16K + Bs 16K); outS reuse
  float* outS = (float*)smem;

  const int t = threadIdx.x;
  const int l = t & 63;
  const int w = t >> 6;
  const int wm = w >> 1, wn = w & 1;

  // XCD-compact swizzle: per-XCD region = 16 n-tiles x 16 m-tiles, 8x8 supertiles
  const int bid = blockIdx.x;
  const int xcd = bid & 7, loc = bid >> 3;
  const int sup = loc >> 6, win = loc & 63;
  const int m0 = ((sup & 1) * 8 + (win & 7)) * 128;
  const int n0 = (xcd * 16 + (sup >> 1) * 8 + (win >> 3)) * 128;

  f32x4 acc[4][4] = {};

  // staging map (BK=64): inst j covers row j*32 + (t>>3), 16B chunk (t&7),
  // with the two 64B k-halves of odd rows swapped (bank de-conflict XOR).
  const int srow = t >> 3;                       // 0..31
  const int schunk = (t & 7) ^ ((srow & 1) << 2); // global 16B-chunk index
  const unsigned short* gA[4];
  const unsigned short* gB[4];
#pragma unroll
  for (int j = 0; j < 4; ++j) {
    gA[j] = xb + (size_t)(m0 + j * 32 + srow) * NIN + schunk * 8;
    gB[j] = bT + (size_t)(n0 + j * 32 + srow) * NIN + schunk * 8;
  }

  const int fr  = l & 15;
  const int frp = fr & 1;            // row parity for the XOR layout
  const int ko16 = (l >> 4) * 16;    // byte offset within a 64 B half

#define ISSUE8(P, KB)                                                     \
  {                                                                       \
    char* dst = smem + (P) * 32768 + t * 16;                              \
    _Pragma("unroll") for (int j = 0; j < 4; ++j) {                       \
      gload_lds16(gA[j] + (KB), dst + j * 4096);                          \
      gload_lds16(gB[j] + (KB), dst + 16384 + j * 4096);                  \
    }                                                                     \
  }

  ISSUE8(0, 0);
  for (int kt = 0; kt < NIN / 64; ++kt) {
    // wait own loads for iter kt (issued one compute-phase ago), then barrier
    asm volatile("s_waitcnt vmcnt(0)\n\ts_barrier" ::: "memory");
    if (kt + 1 < NIN / 64) ISSUE8((kt + 1) & 1, (kt + 1) * 64);
    const char* bA = smem + (kt & 1) * 32768;
    const char* bB = bA + 16384;
#pragma unroll
    for (int c = 0; c < 2; ++c) {
      s16x8 af[4], bfr[4];
      const int hoff = ((c ^ frp) * 64) + ko16;
#pragma unroll
      for (int i = 0; i < 4; ++i)
        af[i] = *(const s16x8*)(bA + (64 * wm + 16 * i + fr) * 128 + hoff);
#pragma unroll
      for (int j = 0; j < 4; ++j)
        bfr[j] = *(const s16x8*)(bB + (64 * wn + 16 * j + fr) * 128 + hoff);
#pragma unroll
      for (int i = 0; i < 4; ++i)
#pragma unroll
        for (int j = 0; j < 4; ++j)
          acc[i][j] = __builtin_amdgcn_mfma_f32_16x16x32_bf16(af[i], bfr[j],
                                                              acc[i][j], 0, 0, 0);
    }
  }
  __syncthreads();

  // epilogue: normalize, pair even/odd columns (A,B), bilinear gate, store
  float  is4[4];
  float4 cf4[4];
  const int g0 = n0 >> 1;
#pragma unroll
  for (int j = 0; j < 4; ++j) {
    const int colg = n0 + 64 * wn + 16 * j + fr;
    is4[j] = invs[colg];
    cf4[j] = coeff[colg >> 1];
  }

  for (int half = 0; half < 2; ++half) {
    if (wm == half) {
#pragma unroll
      for (int i = 0; i < 4; ++i)
#pragma unroll
        for (int j = 0; j < 4; ++j)
#pragma unroll
          for (int r = 0; r < 4; ++r) {
            float v = acc[i][j][r] * is4[j];   // normalized y
            float o = __shfl_xor(v, 1);        // partner column
            if (!(l & 1)) {                    // even lane: col=2g -> A, o=B
              float A = v, B = o;
              float4 p = cf4[j];
              float res = p.x + p.y * A + p.z * B + p.w * A * B;
              const int row = 16 * i + ((l >> 4) << 2) + r;       // 0..63
              const int col = 32 * wn + 8 * j + (fr >> 1);        // 0..63
              outS[row * 68 + col] = res;
            }
          }
    }
    __syncthreads();
#pragma unroll
    for (int it = 0; it < 4; ++it) {
      const int row = it * 16 + (t >> 4);
      const int c4 = (t & 15) * 4;
      float4 vv = *(const float4*)&outS[row * 68 + c4];
      *(float4*)&out[(size_t)(m0 + half * 64 + row) * NGATES + g0 + c4] = vv;
    }
    __syncthreads();
  }
#undef ISSUE8
}

// ---------------------------------------------------------------------------
extern "C" void kernel_launch(void* const* d_in, const int* in_sizes, int n_in,
                              void* d_out, int out_size, void* d_ws,
                              size_t ws_size, hipStream_t stream) {
  const float* x = (const float*)d_in[0];   // [2048][2048]
  const float* w = (const float*)d_in[1];   // [16][8192]
  const float* c = (const float*)d_in[2];   // [2048][8192][2]
  float* out = (float*)d_out;               // [2048][8192]
  char* ws = (char*)d_ws;

  unsigned short* xb   = (unsigned short*)(ws);               // 8,388,608 B
  unsigned short* bT   = (unsigned short*)(ws + 8388608);     // 67,108,864 B
  float*          invs = (float*)(ws + 75497472);             // 65,536 B
  float4*         cf   = (float4*)(ws + 75563008);            // 131,072 B
  float*          ps   = (float*)(ws + 75694080);             // 262,144 B

  gate_coeff_k<<<NGATES / 256, 256, 0, stream>>>(w, cf);
  cvt_x_k<<<(BATCH * NIN / 4) / 256, 256, 0, stream>>>((const float4*)x,
                                                       (ushort4*)xb);
  dim3 sg(NCOL / 64, 4);
  softmax_t_k<<<sg, 256, 0, stream>>>(c, bT, ps);
  inv_k<<<NCOL / 256, 256, 0, stream>>>(ps, invs);
  gemm_gate_k<<<2048, 256, 0, stream>>>(xb, bT, invs, cf, out);
}